// Round 11
// baseline (195.419 us; speedup 1.0000x reference)
//
#include <hip/hip_runtime.h>
#include <hip/hip_bf16.h>
#include <stdint.h>

#define B_N   16
#define C_N   256
#define W_N   64
#define HW_N  4096
#define CK_N  32      // f,g channels
#define CH_N  128     // h channels
#define HWP_N 1024    // pooled spatial
#define MR_N  192     // CK+CK+CH rows in fused conv weight

typedef __attribute__((ext_vector_type(8))) short short8;
typedef __attribute__((ext_vector_type(4))) float f32x4;
typedef __attribute__((ext_vector_type(4))) unsigned uint4v;

#define MFMA(a, b, c) __builtin_amdgcn_mfma_f32_16x16x32_bf16((a), (b), (c), 0, 0, 0)

__device__ __forceinline__ unsigned short f2bf(float f) {
    union { float f; unsigned u; } v; v.f = f;
    unsigned r = v.u + 0x7FFFu + ((v.u >> 16) & 1u);   // RNE
    return (unsigned short)(r >> 16);
}
// round-half-up bf16 pair pack: 3 VALU ops (add, add, v_perm)
__device__ __forceinline__ unsigned packrn(float lo, float hi) {
    unsigned a = __float_as_uint(lo) + 0x8000u;
    unsigned b = __float_as_uint(hi) + 0x8000u;
    return __builtin_amdgcn_perm(b, a, 0x07060302);  // (a>>16)|(b&0xFFFF0000)
}
__device__ __forceinline__ short8 ld8(const void* p) {
    return *reinterpret_cast<const short8*>(p);
}

// ---------------- kernel 0: cast weights to bf16 ----------------
__global__ __launch_bounds__(256) void k_prep(
    const float* __restrict__ wf, const float* __restrict__ wg,
    const float* __restrict__ wh, const float* __restrict__ wv,
    unsigned short* __restrict__ Wc, unsigned short* __restrict__ Wv)
{
    int i = blockIdx.x * 256 + threadIdx.x;
    if (i < MR_N * C_N) {
        int r = i / C_N, c = i % C_N;
        float v = (r < 32) ? wf[r * C_N + c]
                : (r < 64) ? wg[(r - 32) * C_N + c]
                           : wh[(r - 64) * C_N + c];
        Wc[i] = f2bf(v);
    }
    if (i < C_N * CH_N) Wv[i] = f2bf(wv[i]);
}

// ---------------- kernel 1: fused conv1x1 (f,g,h) + 2x2 maxpool ----------------
// f_/g_/h_ all bf16.
// R11: 32px blocks (was 64px), grid 2048. conv_fgh was ~42us vs ~12us traffic
// floor = latency-bound at 16 waves/CU (4 blocks/CU, VGPR ~100 w/ acc[3][4]).
// Halving the px tile: acc[3][2]=24 regs, staging 4 iters, LDS 16KB ->
// if VGPR lands <=64, 8 blocks/CU = 32 waves/CU (double); otherwise finer
// blocks still pipeline staging<->compute across blocks. f/g/h layouts
// unchanged (k_attn untouched). R10 ledger: attn wave count is fixed by
// 16q/wave decomposition -- THIS kernel is where occupancy is expandable.
__global__ __launch_bounds__(256) void k_conv_fgh(
    const float* __restrict__ x, const unsigned short* __restrict__ Wc,
    const float* __restrict__ bfp, const float* __restrict__ bgp, const float* __restrict__ bhp,
    unsigned short* __restrict__ f_, unsigned short* __restrict__ g_, unsigned short* __restrict__ h_)
{
    __shared__ __align__(16) unsigned char lds[32 * 512];
    const int T = threadIdx.x;
    const int lane = T & 63, wid = T >> 6;
    const int blk = blockIdx.x;
    const int b = blk >> 7;
    const int seg = blk & 127;
    const int rp = seg >> 2;        // pooled row 0..31 (x rows 2rp, 2rp+1)
    const int quarter = seg & 3;    // 16-wide column quarter
    const float* xb = x + (size_t)b * C_N * HW_N;

    // stage x -> LDS bf16 (transpose to [32px][ch] with chunk-XOR swizzle)
    #pragma unroll
    for (int i = 0; i < 4; ++i) {
        int task = i * 256 + T;        // 0..1023 = 8 px-quads x 128 ch-pairs
        int pq = task & 7;
        int cp = task >> 3;            // channel pair 0..127
        int px0 = pq * 4;
        int row = 2 * rp + (px0 >> 4);
        int wcol = quarter * 16 + (px0 & 15);
        const float4 v0 = *reinterpret_cast<const float4*>(xb + (size_t)(2 * cp) * HW_N + row * W_N + wcol);
        const float4 v1 = *reinterpret_cast<const float4*>(xb + (size_t)(2 * cp + 1) * HW_N + row * W_N + wcol);
        float vlo[4] = {v0.x, v0.y, v0.z, v0.w};
        float vhi[4] = {v1.x, v1.y, v1.z, v1.w};
        int kc = cp >> 2, co = cp & 3;
        #pragma unroll
        for (int j = 0; j < 4; ++j) {
            int px = px0 + j;
            *reinterpret_cast<unsigned*>(lds + px * 512 + ((kc ^ (px & 15)) << 4) + co * 4)
                = packrn(vlo[j], vhi[j]);
        }
    }
    __syncthreads();

    const int l15 = lane & 15, quad = lane >> 4;
    f32x4 acc[3][2];
    #pragma unroll
    for (int mt = 0; mt < 3; ++mt)
        #pragma unroll
        for (int nt = 0; nt < 2; ++nt)
            acc[mt][nt] = f32x4{0.f, 0.f, 0.f, 0.f};

    const int m0base = wid * 48;
    for (int k0 = 0; k0 < 256; k0 += 32) {
        short8 afr[3];
        #pragma unroll
        for (int mt = 0; mt < 3; ++mt)
            afr[mt] = ld8(Wc + (size_t)(m0base + mt * 16 + l15) * C_N + k0 + quad * 8);
        #pragma unroll
        for (int nt = 0; nt < 2; ++nt) {
            int px = nt * 16 + l15;
            int kc = (k0 >> 3) + quad;
            short8 bfr = ld8(lds + px * 512 + ((kc ^ (px & 15)) << 4));
            #pragma unroll
            for (int mt = 0; mt < 3; ++mt)
                acc[mt][nt] = MFMA(afr[mt], bfr, acc[mt][nt]);
        }
    }

    // epilogue: bias, pool, scatter to f/g/h
    #pragma unroll
    for (int mt = 0; mt < 3; ++mt) {
        int mbase = m0base + mt * 16;
        int mrow0 = mbase + quad * 4;
        float bias[4];
        #pragma unroll
        for (int r = 0; r < 4; ++r) {
            int m = mrow0 + r;
            bias[r] = (m < 32) ? bfp[m] : (m < 64) ? bgp[m - 32] : bhp[m - 64];
        }
        if (mbase < 32) {
            #pragma unroll
            for (int nt = 0; nt < 2; ++nt) {
                int px = nt * 16 + l15;
                int p = (2 * rp + (px >> 4)) * W_N + quarter * 16 + (px & 15);
                uint2 u;
                u.x = packrn(acc[mt][nt][0] + bias[0], acc[mt][nt][1] + bias[1]);
                u.y = packrn(acc[mt][nt][2] + bias[2], acc[mt][nt][3] + bias[3]);
                *reinterpret_cast<uint2*>(f_ + ((size_t)b * HW_N + p) * CK_N + mrow0) = u;
            }
        } else if (mbase < 64) {
            int gc0 = mrow0 - 32;
            float pv[4];
            #pragma unroll
            for (int r = 0; r < 4; ++r) {
                float m1 = fmaxf(acc[mt][0][r], acc[mt][1][r]);   // row pool (px, px+16)
                pv[r] = fmaxf(m1, __shfl_xor(m1, 1)) + bias[r];   // col pool
            }
            if ((lane & 1) == 0) {
                int kp = rp * 32 + quarter * 8 + (l15 >> 1);
                uint2 u;
                u.x = packrn(pv[0], pv[1]);
                u.y = packrn(pv[2], pv[3]);
                *reinterpret_cast<uint2*>(g_ + ((size_t)b * HWP_N + kp) * CK_N + gc0) = u;
            }
        } else {
            int hc0 = mrow0 - 64;
            float pv[4];
            #pragma unroll
            for (int r = 0; r < 4; ++r) {
                float m1 = fmaxf(acc[mt][0][r], acc[mt][1][r]);
                pv[r] = fmaxf(m1, __shfl_xor(m1, 1)) + bias[r];
            }
            #pragma unroll
            for (int r = 0; r < 4; ++r) {
                int lo = (int)(packrn(pv[r], pv[r]) & 0xFFFFu);  // bf16 bits
                int hi = __shfl_down(lo, 2);
                if ((lane & 3) == 0) {
                    int kp2 = rp * 32 + quarter * 8 + (l15 >> 1);
                    *reinterpret_cast<unsigned*>(
                        h_ + ((size_t)b * CH_N + hc0 + r) * HWP_N + kp2)
                        = (unsigned)lo | ((unsigned)hi << 16);
                }
            }
        }
    }
}

// ---------------- kernel 2: fused attention + final conv1x1 + residual ----------------
// R7 structure (verified 56.4/56.9/57.1us, bit-exact): 16 queries/wave,
// 4 waves/block, grid 1024. Fixed-shift softmax. V double-buffered in LDS
// (2 x [128ch][136B]) -- verified-0-conflict layout. PV uses K=32 MFMA via
// permuted-key QK (R2). k_out fused as epilogue via o_lds [64px][264B].
// Ledger: R8 in-register pfO conv (M=256/N=16) regressed (Wv load per MFMA);
// R10 512-thread blocks regressed (total waves fixed at 4096 by 16q/wave --
// grid-limited, not resource-limited; wider barriers cost ~1.5us).
__global__ __launch_bounds__(256, 4) void k_attn(
    const unsigned short* __restrict__ f_, const unsigned short* __restrict__ g_,
    const unsigned short* __restrict__ h_, const unsigned short* __restrict__ Wv,
    const float* __restrict__ bv, const float* __restrict__ x,
    const float* __restrict__ gamma_p, float* __restrict__ out)
{
    __shared__ __align__(16) unsigned char Vl[2 * 17408];
    const int T = threadIdx.x;
    const int lane = T & 63, wid = T >> 6;
    const int l15 = lane & 15, quad = lane >> 4;

    const int blk = blockIdx.x;      // 1024 = 16 b x 64 qtiles(64q)
    const int b = blk >> 6;
    const int q0w = (blk & 63) * 64 + wid * 16;
    const unsigned short* fb = f_ + (size_t)b * HW_N * CK_N;
    const unsigned short* gb = g_ + (size_t)b * HWP_N * CK_N;
    const unsigned short* hb = h_ + (size_t)b * CH_N * HWP_N;

    short8 ffr = ld8(fb + (size_t)(q0w + l15) * CK_N + quad * 8);

    const f32x4 zf = {0.f, 0.f, 0.f, 0.f};
    f32x4 oacc[8];   // [ct]; D row = ch(quad*4+r), col = query(l15)
    #pragma unroll
    for (int ct = 0; ct < 8; ++ct)
        oacc[ct] = f32x4{0.f, 0.f, 0.f, 0.f};
    float lsum = 0.f;

    // staging coords: ch rows sch+32i (i<4), 16B key-chunk skq (0-conflict)
    const int sch = T >> 3, skq = T & 7;
    // permuted in-tile key row for QK A-operand: l15 -> 8*(l15>>2) + (l15&3)
    const int kq = ((l15 >> 2) << 3) | (l15 & 3);

    uint4 vpre[4];
    #pragma unroll
    for (int i = 0; i < 4; ++i)
        vpre[i] = *reinterpret_cast<const uint4*>(hb + (size_t)(sch + i * 32) * HWP_N + skq * 8);
    short8 gcur[4];
    #pragma unroll
    for (int kt = 0; kt < 4; ++kt)
        gcur[kt] = ld8(gb + (size_t)(((kt >> 1) << 5) + ((kt & 1) << 2) + kq) * CK_N + quad * 8);

    for (int c = 0; c < 16; ++c) {
        unsigned char* buf = Vl + (c & 1) * 17408;
        // write chunk c's V (WAR on this buffer was cleared by iter c-1's barrier)
        #pragma unroll
        for (int i = 0; i < 4; ++i) {
            unsigned char* dst = buf + (sch + i * 32) * 136 + skq * 16;
            *reinterpret_cast<uint2*>(dst)     = uint2{vpre[i].x, vpre[i].y};
            *reinterpret_cast<uint2*>(dst + 8) = uint2{vpre[i].z, vpre[i].w};
        }
        // issue chunk c+1 global loads (land during chunk c compute)
        if (c < 15) {
            #pragma unroll
            for (int i = 0; i < 4; ++i)
                vpre[i] = *reinterpret_cast<const uint4*>(
                    hb + (size_t)(sch + i * 32) * HWP_N + (c + 1) * 64 + skq * 8);
        }
        __syncthreads();   // buf writes visible; single barrier per chunk

        // QK: sp[kt] row (quad,r) = key (kt>>1)*32 + (kt&1)*4 + 8*quad + r, col=q(l15)
        f32x4 sp[4];
        #pragma unroll
        for (int kt = 0; kt < 4; ++kt)
            sp[kt] = MFMA(gcur[kt], ffr, zf);
        if (c < 15) {
            #pragma unroll
            for (int kt = 0; kt < 4; ++kt)
                gcur[kt] = ld8(gb + (size_t)((c + 1) * 64 + ((kt >> 1) << 5) + ((kt & 1) << 2) + kq) * CK_N + quad * 8);
        }

        // exp2 fixed shift, accumulate denom, pack straight into K=32 B-frags
        unsigned pw[8];
        float lw = 0.f;
        #pragma unroll
        for (int kt = 0; kt < 4; ++kt) {
            float p0 = __builtin_amdgcn_exp2f(sp[kt][0] * 1.44269504f - 28.85390082f);
            float p1 = __builtin_amdgcn_exp2f(sp[kt][1] * 1.44269504f - 28.85390082f);
            float p2 = __builtin_amdgcn_exp2f(sp[kt][2] * 1.44269504f - 28.85390082f);
            float p3 = __builtin_amdgcn_exp2f(sp[kt][3] * 1.44269504f - 28.85390082f);
            lw += (p0 + p1) + (p2 + p3);
            pw[2 * kt]     = packrn(p0, p1);
            pw[2 * kt + 1] = packrn(p2, p3);
        }
        lsum += lw;
        // B-frag slice t: lane quad holds P[key=t*32+8*quad+j][q=l15], j=0..7
        short8 pfA = __builtin_bit_cast(short8, uint4v{pw[0], pw[1], pw[2], pw[3]});
        short8 pfB = __builtin_bit_cast(short8, uint4v{pw[4], pw[5], pw[6], pw[7]});

        // PV: A = V[ch=ct*16+l15][key=t*32+quad*8+j], two b64 reads per frag
        const int vbase = l15 * 136 + quad * 16;
        #pragma unroll
        for (int ct = 0; ct < 8; ++ct) {
            const unsigned char* p = buf + vbase + ct * 2176;
            uint2 aLo0 = *reinterpret_cast<const uint2*>(p);
            uint2 aLo1 = *reinterpret_cast<const uint2*>(p + 8);
            short8 a0 = __builtin_bit_cast(short8, uint4v{aLo0.x, aLo0.y, aLo1.x, aLo1.y});
            oacc[ct] = MFMA(a0, pfA, oacc[ct]);
            uint2 aHi0 = *reinterpret_cast<const uint2*>(p + 64);
            uint2 aHi1 = *reinterpret_cast<const uint2*>(p + 72);
            short8 a1 = __builtin_bit_cast(short8, uint4v{aHi0.x, aHi0.y, aHi1.x, aHi1.y});
            oacc[ct] = MFMA(a1, pfB, oacc[ct]);
        }
    }

    // reduce denominator across quads (lanes share query = l15), scale
    lsum += __shfl_xor(lsum, 16); lsum += __shfl_xor(lsum, 32);
    const float rl = 1.f / lsum;

    // ---- pack o (bf16, same rounding as before) into LDS [64px][264B] ----
    // Reuses Vl buffer 0 (0..16895 < 17408). No barrier needed first: after
    // chunk 15's in-loop barrier every wave only reads buffer 1 (17408..).
    unsigned char* o_lds = Vl;
    {
        const int row = wid * 16 + l15;   // block-local px
        #pragma unroll
        for (int ct = 0; ct < 8; ++ct) {
            uint2 u;
            u.x = packrn(oacc[ct][0] * rl, oacc[ct][1] * rl);
            u.y = packrn(oacc[ct][2] * rl, oacc[ct][3] * rl);
            *reinterpret_cast<uint2*>(o_lds + row * 264 + (ct * 16 + quad * 4) * 2) = u;
        }
    }
    __syncthreads();   // o_lds visible to all waves (cross-wave px reads)

    // ---- fused final conv: wave wid does oc [wid*64, wid*64+64) x 64 px ----
    const int pxb = (blk & 63) * 64;   // global px base of this block
    const int oc0 = wid * 64;
    f32x4 acc2[4][4];   // [mt][nt]; D row=px(quad*4+r), col=oc(l15)
    #pragma unroll
    for (int mt = 0; mt < 4; ++mt)
        #pragma unroll
        for (int nt = 0; nt < 4; ++nt)
            acc2[mt][nt] = f32x4{0.f, 0.f, 0.f, 0.f};

    #pragma unroll
    for (int k0 = 0; k0 < 128; k0 += 32) {
        short8 ofr[4];   // o A-frags: row px=nt*16+l15, k=k0+quad*8..+7
        #pragma unroll
        for (int nt = 0; nt < 4; ++nt) {
            const unsigned char* p = o_lds + (nt * 16 + l15) * 264 + k0 * 2 + quad * 16;
            uint2 a0 = *reinterpret_cast<const uint2*>(p);
            uint2 a1 = *reinterpret_cast<const uint2*>(p + 8);
            ofr[nt] = __builtin_bit_cast(short8, uint4v{a0.x, a0.y, a1.x, a1.y});
        }
        #pragma unroll
        for (int mt = 0; mt < 4; ++mt) {
            short8 wfr = ld8(Wv + (size_t)(oc0 + mt * 16 + l15) * CH_N + k0 + quad * 8);
            #pragma unroll
            for (int nt = 0; nt < 4; ++nt)
                acc2[mt][nt] = MFMA(ofr[nt], wfr, acc2[mt][nt]);  // A=o(px), B=Wv(oc)
        }
    }

    const float gamma = *gamma_p;
    const float* xb = x + (size_t)b * C_N * HW_N;
    float* outb = out + (size_t)b * C_N * HW_N;
    #pragma unroll
    for (int mt = 0; mt < 4; ++mt) {
        int oc = oc0 + mt * 16 + l15;
        float bvv = bv[oc];
        #pragma unroll
        for (int nt = 0; nt < 4; ++nt) {
            size_t base = (size_t)oc * HW_N + pxb + nt * 16 + quad * 4;
            float4 xv = *reinterpret_cast<const float4*>(xb + base);
            float4 ov;
            ov.x = gamma * (acc2[mt][nt][0] + bvv) + xv.x;
            ov.y = gamma * (acc2[mt][nt][1] + bvv) + xv.y;
            ov.z = gamma * (acc2[mt][nt][2] + bvv) + xv.z;
            ov.w = gamma * (acc2[mt][nt][3] + bvv) + xv.w;
            *reinterpret_cast<float4*>(outb + base) = ov;
        }
    }
}

// ---------------- launch ----------------
extern "C" void kernel_launch(void* const* d_in, const int* in_sizes, int n_in,
                              void* d_out, int out_size, void* d_ws, size_t ws_size,
                              hipStream_t stream) {
    const float* x     = (const float*)d_in[0];
    const float* wf    = (const float*)d_in[1];
    const float* bf    = (const float*)d_in[2];
    const float* wg    = (const float*)d_in[3];
    const float* bg    = (const float*)d_in[4];
    const float* wh    = (const float*)d_in[5];
    const float* bh    = (const float*)d_in[6];
    const float* wv    = (const float*)d_in[7];
    const float* bv    = (const float*)d_in[8];
    const float* gamma = (const float*)d_in[9];
    float* out = (float*)d_out;
    char* ws = (char*)d_ws;

    unsigned short* f_ = (unsigned short*)(ws);                 //  4,194,304 B
    unsigned short* g_ = (unsigned short*)(ws + 4194304);       //  1,048,576 B
    unsigned short* h_ = (unsigned short*)(ws + 5242880);       //  4,194,304 B
    unsigned short* Wc = (unsigned short*)(ws + 26214400);      //     98,304 B
    unsigned short* Wv = (unsigned short*)(ws + 26312704);      //     65,536 B

    k_prep<<<192, 256, 0, stream>>>(wf, wg, wh, wv, Wc, Wv);
    k_conv_fgh<<<2048, 256, 0, stream>>>(x, Wc, bf, bg, bh, f_, g_, h_);
    k_attn<<<1024, 256, 0, stream>>>(f_, g_, h_, Wv, bv, x, gamma, out);
}

// Round 13
// 181.468 us; speedup vs baseline: 1.0769x; 1.0769x over previous
//
#include <hip/hip_runtime.h>
#include <hip/hip_bf16.h>
#include <stdint.h>

#define B_N   16
#define C_N   256
#define W_N   64
#define HW_N  4096
#define CK_N  32      // f,g channels
#define CH_N  128     // h channels
#define HWP_N 1024    // pooled spatial
#define MR_N  192     // CK+CK+CH rows in fused conv weight

typedef __attribute__((ext_vector_type(8))) short short8;
typedef __attribute__((ext_vector_type(4))) float f32x4;
typedef __attribute__((ext_vector_type(4))) unsigned uint4v;

#define MFMA(a, b, c) __builtin_amdgcn_mfma_f32_16x16x32_bf16((a), (b), (c), 0, 0, 0)

__device__ __forceinline__ unsigned short f2bf(float f) {
    union { float f; unsigned u; } v; v.f = f;
    unsigned r = v.u + 0x7FFFu + ((v.u >> 16) & 1u);   // RNE
    return (unsigned short)(r >> 16);
}
// round-half-up bf16 pair pack: 3 VALU ops (add, add, v_perm)
__device__ __forceinline__ unsigned packrn(float lo, float hi) {
    unsigned a = __float_as_uint(lo) + 0x8000u;
    unsigned b = __float_as_uint(hi) + 0x8000u;
    return __builtin_amdgcn_perm(b, a, 0x07060302);  // (a>>16)|(b&0xFFFF0000)
}
__device__ __forceinline__ short8 ld8(const void* p) {
    return *reinterpret_cast<const short8*>(p);
}

// ---------------- kernel 0: cast weights to bf16 ----------------
__global__ __launch_bounds__(256) void k_prep(
    const float* __restrict__ wf, const float* __restrict__ wg,
    const float* __restrict__ wh, const float* __restrict__ wv,
    unsigned short* __restrict__ Wc, unsigned short* __restrict__ Wv)
{
    int i = blockIdx.x * 256 + threadIdx.x;
    if (i < MR_N * C_N) {
        int r = i / C_N, c = i % C_N;
        float v = (r < 32) ? wf[r * C_N + c]
                : (r < 64) ? wg[(r - 32) * C_N + c]
                           : wh[(r - 64) * C_N + c];
        Wc[i] = f2bf(v);
    }
    if (i < C_N * CH_N) Wv[i] = f2bf(wv[i]);
}

// ---------------- kernel 1: fused conv1x1 (f,g,h) + 2x2 maxpool ----------------
// f_/g_/h_ all bf16. R7 form (best measured ~40us).
// Ledger: R9 load-hoist neutral-negative; R11 32px tile regressed (~50us:
// per-block overheads double, no occupancy gain). 64px is the sweet spot.
__global__ __launch_bounds__(256) void k_conv_fgh(
    const float* __restrict__ x, const unsigned short* __restrict__ Wc,
    const float* __restrict__ bfp, const float* __restrict__ bgp, const float* __restrict__ bhp,
    unsigned short* __restrict__ f_, unsigned short* __restrict__ g_, unsigned short* __restrict__ h_)
{
    __shared__ __align__(16) unsigned char lds[64 * 512];
    const int T = threadIdx.x;
    const int lane = T & 63, wid = T >> 6;
    const int blk = blockIdx.x;
    const int b = blk >> 6;
    const int seg = blk & 63;
    const int rp = seg >> 1;     // pooled row 0..31
    const int half = seg & 1;    // which 32-wide half of the row pair
    const float* xb = x + (size_t)b * C_N * HW_N;

    // stage x -> LDS bf16 (transpose to [px][ch] with chunk-XOR swizzle)
    #pragma unroll
    for (int i = 0; i < 8; ++i) {
        int task = i * 256 + T;        // 0..2047 = 16 px-quads x 128 ch-pairs
        int pq = task & 15;
        int cp = task >> 4;            // channel pair 0..127
        int px0 = pq * 4;
        int row = 2 * rp + (px0 >> 5);
        int wcol = half * 32 + (px0 & 31);
        const float4 v0 = *reinterpret_cast<const float4*>(xb + (size_t)(2 * cp) * HW_N + row * W_N + wcol);
        const float4 v1 = *reinterpret_cast<const float4*>(xb + (size_t)(2 * cp + 1) * HW_N + row * W_N + wcol);
        float vlo[4] = {v0.x, v0.y, v0.z, v0.w};
        float vhi[4] = {v1.x, v1.y, v1.z, v1.w};
        int kc = cp >> 2, co = cp & 3;
        #pragma unroll
        for (int j = 0; j < 4; ++j) {
            int px = px0 + j;
            *reinterpret_cast<unsigned*>(lds + px * 512 + ((kc ^ (px & 31)) << 4) + co * 4)
                = packrn(vlo[j], vhi[j]);
        }
    }
    __syncthreads();

    const int l15 = lane & 15, quad = lane >> 4;
    f32x4 acc[3][4];
    #pragma unroll
    for (int mt = 0; mt < 3; ++mt)
        #pragma unroll
        for (int nt = 0; nt < 4; ++nt)
            acc[mt][nt] = f32x4{0.f, 0.f, 0.f, 0.f};

    const int m0base = wid * 48;
    for (int k0 = 0; k0 < 256; k0 += 32) {
        short8 afr[3];
        #pragma unroll
        for (int mt = 0; mt < 3; ++mt)
            afr[mt] = ld8(Wc + (size_t)(m0base + mt * 16 + l15) * C_N + k0 + quad * 8);
        #pragma unroll
        for (int nt = 0; nt < 4; ++nt) {
            int px = nt * 16 + l15;
            int kc = (k0 >> 3) + quad;
            short8 bfr = ld8(lds + px * 512 + ((kc ^ (px & 31)) << 4));
            #pragma unroll
            for (int mt = 0; mt < 3; ++mt)
                acc[mt][nt] = MFMA(afr[mt], bfr, acc[mt][nt]);
        }
    }

    // epilogue: bias, pool, scatter to f/g/h
    #pragma unroll
    for (int mt = 0; mt < 3; ++mt) {
        int mbase = m0base + mt * 16;
        int mrow0 = mbase + quad * 4;
        float bias[4];
        #pragma unroll
        for (int r = 0; r < 4; ++r) {
            int m = mrow0 + r;
            bias[r] = (m < 32) ? bfp[m] : (m < 64) ? bgp[m - 32] : bhp[m - 64];
        }
        if (mbase < 32) {
            #pragma unroll
            for (int nt = 0; nt < 4; ++nt) {
                int px = nt * 16 + l15;
                int p = (2 * rp + (px >> 5)) * W_N + half * 32 + (px & 31);
                uint2 u;
                u.x = packrn(acc[mt][nt][0] + bias[0], acc[mt][nt][1] + bias[1]);
                u.y = packrn(acc[mt][nt][2] + bias[2], acc[mt][nt][3] + bias[3]);
                *reinterpret_cast<uint2*>(f_ + ((size_t)b * HW_N + p) * CK_N + mrow0) = u;
            }
        } else if (mbase < 64) {
            int gc0 = mrow0 - 32;
            #pragma unroll
            for (int nt = 0; nt < 2; ++nt) {
                float pv[4];
                #pragma unroll
                for (int r = 0; r < 4; ++r) {
                    float m1 = fmaxf(acc[mt][nt][r], acc[mt][nt + 2][r]);
                    pv[r] = fmaxf(m1, __shfl_xor(m1, 1)) + bias[r];
                }
                if ((lane & 1) == 0) {
                    int kp = rp * 32 + half * 16 + ((nt * 16 + l15) >> 1);
                    uint2 u;
                    u.x = packrn(pv[0], pv[1]);
                    u.y = packrn(pv[2], pv[3]);
                    *reinterpret_cast<uint2*>(g_ + ((size_t)b * HWP_N + kp) * CK_N + gc0) = u;
                }
            }
        } else {
            int hc0 = mrow0 - 64;
            #pragma unroll
            for (int nt = 0; nt < 2; ++nt) {
                float pv[4];
                #pragma unroll
                for (int r = 0; r < 4; ++r) {
                    float m1 = fmaxf(acc[mt][nt][r], acc[mt][nt + 2][r]);
                    pv[r] = fmaxf(m1, __shfl_xor(m1, 1)) + bias[r];
                }
                #pragma unroll
                for (int r = 0; r < 4; ++r) {
                    int lo = (int)(packrn(pv[r], pv[r]) & 0xFFFFu);  // bf16 bits
                    int hi = __shfl_down(lo, 2);
                    if ((lane & 3) == 0) {
                        int kp2 = rp * 32 + half * 16 + nt * 8 + (l15 >> 1);
                        *reinterpret_cast<unsigned*>(
                            h_ + ((size_t)b * CH_N + hc0 + r) * HWP_N + kp2)
                            = (unsigned)lo | ((unsigned)hi << 16);
                    }
                }
            }
        }
    }
}

// ---------------- kernel 2: fused attention + final conv1x1 + residual ----------------
// R7 structure (verified 56.4/56.9/57.1us, bit-exact) + R12 XCD-chunked
// blockIdx swizzle: logical = (hw%8)*128 + hw/8 (bijective, 1024%8==0).
// Each XCD owns 128 consecutive logical blocks = 2 whole batches -> that
// batch's g(64KB)/h(256KB) are fetched into its private L2 ONCE instead of
// once per XCD (~8x h over-fetch seen as FETCH 55.7MB vs ~42MB ideal), and
// staging loads become L2-hits (~200cy vs ~900cy) -> deeper prefetch cover.
// Ledger: R8 in-register pfO conv regressed (Wv load per MFMA); R10 512-thr
// blocks regressed (wave count fixed by 16q/wave decomposition).
__global__ __launch_bounds__(256, 4) void k_attn(
    const unsigned short* __restrict__ f_, const unsigned short* __restrict__ g_,
    const unsigned short* __restrict__ h_, const unsigned short* __restrict__ Wv,
    const float* __restrict__ bv, const float* __restrict__ x,
    const float* __restrict__ gamma_p, float* __restrict__ out)
{
    __shared__ __align__(16) unsigned char Vl[2 * 17408];
    const int T = threadIdx.x;
    const int lane = T & 63, wid = T >> 6;
    const int l15 = lane & 15, quad = lane >> 4;

    // XCD-chunked swizzle (T1): hw blocks with equal hw%8 sit on one XCD.
    const int hwblk = blockIdx.x;
    const int blk = (hwblk & 7) * 128 + (hwblk >> 3);   // 1024 = 16 b x 64 qtiles
    const int b = blk >> 6;
    const int q0w = (blk & 63) * 64 + wid * 16;
    const unsigned short* fb = f_ + (size_t)b * HW_N * CK_N;
    const unsigned short* gb = g_ + (size_t)b * HWP_N * CK_N;
    const unsigned short* hb = h_ + (size_t)b * CH_N * HWP_N;

    short8 ffr = ld8(fb + (size_t)(q0w + l15) * CK_N + quad * 8);

    const f32x4 zf = {0.f, 0.f, 0.f, 0.f};
    f32x4 oacc[8];   // [ct]; D row = ch(quad*4+r), col = query(l15)
    #pragma unroll
    for (int ct = 0; ct < 8; ++ct)
        oacc[ct] = f32x4{0.f, 0.f, 0.f, 0.f};
    float lsum = 0.f;

    // staging coords: ch rows sch+32i (i<4), 16B key-chunk skq (0-conflict)
    const int sch = T >> 3, skq = T & 7;
    // permuted in-tile key row for QK A-operand: l15 -> 8*(l15>>2) + (l15&3)
    const int kq = ((l15 >> 2) << 3) | (l15 & 3);

    uint4 vpre[4];
    #pragma unroll
    for (int i = 0; i < 4; ++i)
        vpre[i] = *reinterpret_cast<const uint4*>(hb + (size_t)(sch + i * 32) * HWP_N + skq * 8);
    short8 gcur[4];
    #pragma unroll
    for (int kt = 0; kt < 4; ++kt)
        gcur[kt] = ld8(gb + (size_t)(((kt >> 1) << 5) + ((kt & 1) << 2) + kq) * CK_N + quad * 8);

    for (int c = 0; c < 16; ++c) {
        unsigned char* buf = Vl + (c & 1) * 17408;
        // write chunk c's V (WAR on this buffer was cleared by iter c-1's barrier)
        #pragma unroll
        for (int i = 0; i < 4; ++i) {
            unsigned char* dst = buf + (sch + i * 32) * 136 + skq * 16;
            *reinterpret_cast<uint2*>(dst)     = uint2{vpre[i].x, vpre[i].y};
            *reinterpret_cast<uint2*>(dst + 8) = uint2{vpre[i].z, vpre[i].w};
        }
        // issue chunk c+1 global loads (land during chunk c compute)
        if (c < 15) {
            #pragma unroll
            for (int i = 0; i < 4; ++i)
                vpre[i] = *reinterpret_cast<const uint4*>(
                    hb + (size_t)(sch + i * 32) * HWP_N + (c + 1) * 64 + skq * 8);
        }
        __syncthreads();   // buf writes visible; single barrier per chunk

        // QK: sp[kt] row (quad,r) = key (kt>>1)*32 + (kt&1)*4 + 8*quad + r, col=q(l15)
        f32x4 sp[4];
        #pragma unroll
        for (int kt = 0; kt < 4; ++kt)
            sp[kt] = MFMA(gcur[kt], ffr, zf);
        if (c < 15) {
            #pragma unroll
            for (int kt = 0; kt < 4; ++kt)
                gcur[kt] = ld8(gb + (size_t)((c + 1) * 64 + ((kt >> 1) << 5) + ((kt & 1) << 2) + kq) * CK_N + quad * 8);
        }

        // exp2 fixed shift, accumulate denom, pack straight into K=32 B-frags
        unsigned pw[8];
        float lw = 0.f;
        #pragma unroll
        for (int kt = 0; kt < 4; ++kt) {
            float p0 = __builtin_amdgcn_exp2f(sp[kt][0] * 1.44269504f - 28.85390082f);
            float p1 = __builtin_amdgcn_exp2f(sp[kt][1] * 1.44269504f - 28.85390082f);
            float p2 = __builtin_amdgcn_exp2f(sp[kt][2] * 1.44269504f - 28.85390082f);
            float p3 = __builtin_amdgcn_exp2f(sp[kt][3] * 1.44269504f - 28.85390082f);
            lw += (p0 + p1) + (p2 + p3);
            pw[2 * kt]     = packrn(p0, p1);
            pw[2 * kt + 1] = packrn(p2, p3);
        }
        lsum += lw;
        // B-frag slice t: lane quad holds P[key=t*32+8*quad+j][q=l15], j=0..7
        short8 pfA = __builtin_bit_cast(short8, uint4v{pw[0], pw[1], pw[2], pw[3]});
        short8 pfB = __builtin_bit_cast(short8, uint4v{pw[4], pw[5], pw[6], pw[7]});

        // PV: A = V[ch=ct*16+l15][key=t*32+quad*8+j], two b64 reads per frag
        const int vbase = l15 * 136 + quad * 16;
        #pragma unroll
        for (int ct = 0; ct < 8; ++ct) {
            const unsigned char* p = buf + vbase + ct * 2176;
            uint2 aLo0 = *reinterpret_cast<const uint2*>(p);
            uint2 aLo1 = *reinterpret_cast<const uint2*>(p + 8);
            short8 a0 = __builtin_bit_cast(short8, uint4v{aLo0.x, aLo0.y, aLo1.x, aLo1.y});
            oacc[ct] = MFMA(a0, pfA, oacc[ct]);
            uint2 aHi0 = *reinterpret_cast<const uint2*>(p + 64);
            uint2 aHi1 = *reinterpret_cast<const uint2*>(p + 72);
            short8 a1 = __builtin_bit_cast(short8, uint4v{aHi0.x, aHi0.y, aHi1.x, aHi1.y});
            oacc[ct] = MFMA(a1, pfB, oacc[ct]);
        }
    }

    // reduce denominator across quads (lanes share query = l15), scale
    lsum += __shfl_xor(lsum, 16); lsum += __shfl_xor(lsum, 32);
    const float rl = 1.f / lsum;

    // ---- pack o (bf16, same rounding as before) into LDS [64px][264B] ----
    // Reuses Vl buffer 0 (0..16895 < 17408). No barrier needed first: after
    // chunk 15's in-loop barrier every wave only reads buffer 1 (17408..).
    unsigned char* o_lds = Vl;
    {
        const int row = wid * 16 + l15;   // block-local px
        #pragma unroll
        for (int ct = 0; ct < 8; ++ct) {
            uint2 u;
            u.x = packrn(oacc[ct][0] * rl, oacc[ct][1] * rl);
            u.y = packrn(oacc[ct][2] * rl, oacc[ct][3] * rl);
            *reinterpret_cast<uint2*>(o_lds + row * 264 + (ct * 16 + quad * 4) * 2) = u;
        }
    }
    __syncthreads();   // o_lds visible to all waves (cross-wave px reads)

    // ---- fused final conv: wave wid does oc [wid*64, wid*64+64) x 64 px ----
    const int pxb = (blk & 63) * 64;   // global px base of this block
    const int oc0 = wid * 64;
    f32x4 acc2[4][4];   // [mt][nt]; D row=px(quad*4+r), col=oc(l15)
    #pragma unroll
    for (int mt = 0; mt < 4; ++mt)
        #pragma unroll
        for (int nt = 0; nt < 4; ++nt)
            acc2[mt][nt] = f32x4{0.f, 0.f, 0.f, 0.f};

    #pragma unroll
    for (int k0 = 0; k0 < 128; k0 += 32) {
        short8 ofr[4];   // o A-frags: row px=nt*16+l15, k=k0+quad*8..+7
        #pragma unroll
        for (int nt = 0; nt < 4; ++nt) {
            const unsigned char* p = o_lds + (nt * 16 + l15) * 264 + k0 * 2 + quad * 16;
            uint2 a0 = *reinterpret_cast<const uint2*>(p);
            uint2 a1 = *reinterpret_cast<const uint2*>(p + 8);
            ofr[nt] = __builtin_bit_cast(short8, uint4v{a0.x, a0.y, a1.x, a1.y});
        }
        #pragma unroll
        for (int mt = 0; mt < 4; ++mt) {
            short8 wfr = ld8(Wv + (size_t)(oc0 + mt * 16 + l15) * CH_N + k0 + quad * 8);
            #pragma unroll
            for (int nt = 0; nt < 4; ++nt)
                acc2[mt][nt] = MFMA(ofr[nt], wfr, acc2[mt][nt]);  // A=o(px), B=Wv(oc)
        }
    }

    const float gamma = *gamma_p;
    const float* xb = x + (size_t)b * C_N * HW_N;
    float* outb = out + (size_t)b * C_N * HW_N;
    #pragma unroll
    for (int mt = 0; mt < 4; ++mt) {
        int oc = oc0 + mt * 16 + l15;
        float bvv = bv[oc];
        #pragma unroll
        for (int nt = 0; nt < 4; ++nt) {
            size_t base = (size_t)oc * HW_N + pxb + nt * 16 + quad * 4;
            float4 xv = *reinterpret_cast<const float4*>(xb + base);
            float4 ov;
            ov.x = gamma * (acc2[mt][nt][0] + bvv) + xv.x;
            ov.y = gamma * (acc2[mt][nt][1] + bvv) + xv.y;
            ov.z = gamma * (acc2[mt][nt][2] + bvv) + xv.z;
            ov.w = gamma * (acc2[mt][nt][3] + bvv) + xv.w;
            *reinterpret_cast<float4*>(outb + base) = ov;
        }
    }
}

// ---------------- launch ----------------
extern "C" void kernel_launch(void* const* d_in, const int* in_sizes, int n_in,
                              void* d_out, int out_size, void* d_ws, size_t ws_size,
                              hipStream_t stream) {
    const float* x     = (const float*)d_in[0];
    const float* wf    = (const float*)d_in[1];
    const float* bf    = (const float*)d_in[2];
    const float* wg    = (const float*)d_in[3];
    const float* bg    = (const float*)d_in[4];
    const float* wh    = (const float*)d_in[5];
    const float* bh    = (const float*)d_in[6];
    const float* wv    = (const float*)d_in[7];
    const float* bv    = (const float*)d_in[8];
    const float* gamma = (const float*)d_in[9];
    float* out = (float*)d_out;
    char* ws = (char*)d_ws;

    unsigned short* f_ = (unsigned short*)(ws);                 //  4,194,304 B
    unsigned short* g_ = (unsigned short*)(ws + 4194304);       //  1,048,576 B
    unsigned short* h_ = (unsigned short*)(ws + 5242880);       //  4,194,304 B
    unsigned short* Wc = (unsigned short*)(ws + 26214400);      //     98,304 B
    unsigned short* Wv = (unsigned short*)(ws + 26312704);      //     65,536 B

    k_prep<<<192, 256, 0, stream>>>(wf, wg, wh, wv, Wc, Wv);
    k_conv_fgh<<<1024, 256, 0, stream>>>(x, Wc, bf, bg, bh, f_, g_, h_);
    k_attn<<<1024, 256, 0, stream>>>(f_, g_, h_, Wv, bv, x, gamma, out);
}